// Round 6
// baseline (454.500 us; speedup 1.0000x reference)
//
#include <hip/hip_runtime.h>
#include <math.h>
#include <stdint.h>

#define Bsz 8
#define Lsz 8192
#define D 256
#define NROWS (Bsz*Lsz)      // 65536
#define NC 128               // chunks per sequence
#define CL (Lsz/NC)          // 64
#define LN_EPS 1e-6f

typedef float f32x4 __attribute__((ext_vector_type(4)));
typedef short bf16x8 __attribute__((ext_vector_type(8)));
typedef uint32_t __attribute__((address_space(3))) as3_u32;
typedef const uint32_t __attribute__((address_space(1))) as1_u32;

__device__ __forceinline__ float gelu_tanh(float v){
    const float k0 = 0.7978845608028654f;   // sqrt(2/pi)
    const float k1 = 0.044715f;
    float inner = k0 * fmaf(k1*v*v, v, v);
    return 0.5f * v * (1.0f + tanhf(inner));
}
__device__ __forceinline__ uint16_t bf16_rne(float f){
    uint32_t u = __float_as_uint(f);
    return (uint16_t)((u + 0x7fffu + ((u>>16)&1u)) >> 16);
}
__device__ __forceinline__ float bf16_to_f(uint16_t h){
    return __uint_as_float(((uint32_t)h)<<16);
}

// ---- prep: split weights to bf16 hi/lo planes (B-layout [N][K]) ------------
__global__ __launch_bounds__(256)
void k_prep(const float* __restrict__ B_re, const float* __restrict__ B_im,
            const float* __restrict__ C_re, const float* __restrict__ C_im,
            const float* __restrict__ W, const float* __restrict__ ln_scale,
            short* __restrict__ b1_hi, short* __restrict__ b1_lo,
            short* __restrict__ b2_hi, short* __restrict__ b2_lo,
            short* __restrict__ b3_hi, short* __restrict__ b3_lo){
    int i = blockIdx.x*256 + threadIdx.x;   // 131072
    {   // b1 [512][256]
        int n = i >> 8, d = i & 255;
        float v = (n < 256 ? B_re[n*256 + d] : B_im[(n-256)*256 + d]) * ln_scale[d];
        uint16_t hi = bf16_rne(v);
        b1_hi[i] = (short)hi;
        b1_lo[i] = (short)bf16_rne(v - bf16_to_f(hi));
    }
    {   // b2 [256][512], K-interleaved re/im
        int n = i >> 9, k = i & 511, h = k >> 1;
        float v = (k & 1) ? -C_im[n*256 + h] : C_re[n*256 + h];
        uint16_t hi = bf16_rne(v);
        b2_hi[i] = (short)hi;
        b2_lo[i] = (short)bf16_rne(v - bf16_to_f(hi));
    }
    if (i < 256*256){   // b3 [256][256]
        float v = W[i];
        uint16_t hi = bf16_rne(v);
        b3_hi[i] = (short)hi;
        b3_lo[i] = (short)bf16_rne(v - bf16_to_f(hi));
    }
}

__global__ __launch_bounds__(256)
void k_prep_t(const float* __restrict__ B_re, const float* __restrict__ B_im,
              const float* __restrict__ ln_scale, const float* __restrict__ ln_bias,
              float* __restrict__ t1, float* __restrict__ t2){
    int n = blockIdx.x*256 + threadIdx.x;
    if (n >= 512) return;
    const float* src = (n < 256) ? &B_re[n*256] : &B_im[(n-256)*256];
    float s1 = 0.f, s2 = 0.f;
    for (int d = 0; d < 256; d++){
        float b = src[d];
        s1 = fmaf(ln_scale[d], b, s1);
        s2 = fmaf(ln_bias[d],  b, s2);
    }
    t1[n] = s1; t2[n] = s2;
}

// ---- stats: LN (mu, rstd) per row + materialize xhi/xlo bf16 planes --------
__global__ __launch_bounds__(256)
void k_stats(const float* __restrict__ x, float* __restrict__ mu_arr,
             float* __restrict__ rstd_arr, short* __restrict__ xhi,
             short* __restrict__ xlo){
    int r0 = blockIdx.x * 16;
    int t = threadIdx.x;
    int wave = t >> 6, lane = t & 63;
    for (int rr = wave; rr < 16; rr += 4){
        const float* xr = x + (size_t)(r0 + rr) * D;
        float v[4]; float s = 0.f;
        #pragma unroll
        for (int i=0;i<4;i++){ v[i] = xr[lane + 64*i]; s += v[i]; }
        #pragma unroll
        for (int off=32; off; off>>=1) s += __shfl_xor(s, off);
        float mu = s * (1.0f/D);
        float vs = 0.f;
        #pragma unroll
        for (int i=0;i<4;i++){ float dd = v[i]-mu; vs += dd*dd; }
        #pragma unroll
        for (int off=32; off; off>>=1) vs += __shfl_xor(vs, off);
        float rstd = rsqrtf(vs*(1.0f/D) + LN_EPS);
        if (lane == 0){ mu_arr[r0+rr] = mu; rstd_arr[r0+rr] = rstd; }
        size_t rb = (size_t)(r0+rr)*D;
        #pragma unroll
        for (int i=0;i<4;i++){
            int dd = lane + 64*i;
            uint16_t hb = bf16_rne(v[i]);
            xhi[rb+dd] = (short)hb;
            xlo[rb+dd] = (short)bf16_rne(v[i] - bf16_to_f(hb));
        }
    }
}

// ---- 256x256 MFMA GEMM: 8-phase schedule (T3+T4+T5), split-bf16 3-product --
// LDS: 2 bufs x 4 planes (Ahi,Alo,Bhi,Blo) x 8192 shorts = 128 KB.
// Frag-major chunks: 16B chunk c = F*64 + kg*16 + r holds row F*16+r, k-slice
// kg (8 shorts) -> every frag ds_read_b128 is 256B-contiguous per 16-lane grp.
// Per K-step (BK=32): 8 phases, each {ds_read frags | 2 gload_lds (ph 0-3,
// next tile) -> barrier -> lgkmcnt(0) -> setprio(1) -> 12 MFMA -> setprio(0)
// -> barrier}; single vmcnt(0) at phase 7 (loads issued >=4 phases earlier).
#define GLD16(gp, lp) __builtin_amdgcn_global_load_lds((as1_u32*)(gp), (as3_u32*)(lp), 16, 0, 0)

#define ARD(mh) \
    a0h = *(const bf16x8*)&LA [((ga + 2*(mh)  )*64 + lgrp*16 + lrow)*8]; \
    a0l = *(const bf16x8*)&LAl[((ga + 2*(mh)  )*64 + lgrp*16 + lrow)*8]; \
    a1h = *(const bf16x8*)&LA [((ga + 2*(mh)+1)*64 + lgrp*16 + lrow)*8]; \
    a1l = *(const bf16x8*)&LAl[((ga + 2*(mh)+1)*64 + lgrp*16 + lrow)*8];

#define BRD(nf, BH, BL) \
    BH = *(const bf16x8*)&LB [((gb + (nf))*64 + lgrp*16 + lrow)*8]; \
    BL = *(const bf16x8*)&LBl[((gb + (nf))*64 + lgrp*16 + lrow)*8];

#define MM3(mf, nf, AH, AL, BH, BL) \
    acc[mf][nf] = __builtin_amdgcn_mfma_f32_16x16x32_bf16(AH, BH, acc[mf][nf],0,0,0); \
    acc[mf][nf] = __builtin_amdgcn_mfma_f32_16x16x32_bf16(AH, BL, acc[mf][nf],0,0,0); \
    acc[mf][nf] = __builtin_amdgcn_mfma_f32_16x16x32_bf16(AL, BH, acc[mf][nf],0,0,0);

#define FENCE_MFMA \
    __builtin_amdgcn_s_barrier(); \
    asm volatile("s_waitcnt lgkmcnt(0)" ::: "memory"); \
    __builtin_amdgcn_sched_barrier(0); \
    __builtin_amdgcn_s_setprio(1);

#define ENDPH \
    __builtin_amdgcn_s_setprio(0); \
    __builtin_amdgcn_s_barrier();

template<int MODE>
__global__ __launch_bounds__(512, 2)
void k_gemm(const short* __restrict__ Ahi_g, const short* __restrict__ Alo_g,
            const short* __restrict__ Bhi_g, const short* __restrict__ Blo_g,
            const float* __restrict__ x,
            const float* __restrict__ mu_arr, const float* __restrict__ rs_arr,
            const float* __restrict__ t1, const float* __restrict__ t2,
            const float* __restrict__ nu_log,
            const float* __restrict__ ln_scale, const float* __restrict__ ln_bias,
            const float* __restrict__ d_skip, const float* __restrict__ bvec,
            float* __restrict__ outA, float* __restrict__ outB,
            short* __restrict__ gh, short* __restrict__ gl){
    constexpr int K   = (MODE==2) ? 512 : 256;
    constexpr int NYB = (MODE==1) ? 2 : 1;
    constexpr int NT  = K/32;
    __shared__ __align__(16) short lds[2][4][8192];
    const int t = threadIdx.x;
    const int wv = t >> 6, lane = t & 63;
    const int lgrp = lane >> 4, lrow = lane & 15;
    const int r0 = (blockIdx.x / NYB) * 256;
    const int n0 = (blockIdx.x % NYB) * 256;
    const int mr = (wv >> 2) * 128;    // 2 m-waves x 4 n-waves, 128x64 each
    const int nc = (wv & 3) * 64;
    const int ga = (wv >> 2) * 8;
    const int gb = (wv & 3) * 4;

    // staging sources: plane P, call q in {0,1}: row (2wv+q)*16+lrow, k lgrp*8
    const size_t arow = (size_t)(r0 + 2*wv*16 + lrow) * K + lgrp*8;
    const size_t brow = (size_t)(n0 + 2*wv*16 + lrow) * K + lgrp*8;
    const short* pA0h = Ahi_g + arow;
    const short* pA0l = Alo_g + arow;
    const short* pB0h = Bhi_g + brow;
    const short* pB0l = Blo_g + brow;
    const size_t h16 = (size_t)16 * K;     // +16 rows (call q=1)
    const int c0 = 2*wv*512, c1 = (2*wv+1)*512;   // LDS chunk bases (shorts)

    f32x4 acc[8][4];
    #pragma unroll
    for (int mf=0;mf<8;mf++)
    #pragma unroll
    for (int nf=0;nf<4;nf++) acc[mf][nf] = (f32x4){0.f,0.f,0.f,0.f};

    // prologue: stage tile 0 into buf 0
    GLD16(pA0h,       &lds[0][0][c0]); GLD16(pA0h + h16, &lds[0][0][c1]);
    GLD16(pA0l,       &lds[0][1][c0]); GLD16(pA0l + h16, &lds[0][1][c1]);
    GLD16(pB0h,       &lds[0][2][c0]); GLD16(pB0h + h16, &lds[0][2][c1]);
    GLD16(pB0l,       &lds[0][3][c0]); GLD16(pB0l + h16, &lds[0][3][c1]);
    asm volatile("s_waitcnt vmcnt(0)" ::: "memory");
    __builtin_amdgcn_s_barrier();

    #pragma unroll 1
    for (int kt = 0; kt < NT; ++kt){
        const int cb = kt & 1, nb = cb ^ 1;
        const short* LA  = &lds[cb][0][0];
        const short* LAl = &lds[cb][1][0];
        const short* LB  = &lds[cb][2][0];
        const short* LBl = &lds[cb][3][0];
        const int kn = (kt+1)*32;          // next-tile k offset (shorts)
        const bool pf = (kt+1 < NT);
        bf16x8 bh0,bl0,bh1,bl1,bh2,bl2,bh3,bl3;
        bf16x8 a0h,a0l,a1h,a1l;

        // ---- phase 0 (mf 0,1 x nf 0,1) ----
        ARD(0); BRD(0,bh0,bl0); BRD(1,bh1,bl1);
        if (pf){ GLD16(pA0h+kn, &lds[nb][0][c0]); GLD16(pA0h+h16+kn, &lds[nb][0][c1]); }
        FENCE_MFMA;
        MM3(0,0,a0h,a0l,bh0,bl0); MM3(0,1,a0h,a0l,bh1,bl1);
        MM3(1,0,a1h,a1l,bh0,bl0); MM3(1,1,a1h,a1l,bh1,bl1);
        ENDPH;
        // ---- phase 1 (mf 0,1 x nf 2,3) ----
        BRD(2,bh2,bl2); BRD(3,bh3,bl3);
        if (pf){ GLD16(pA0l+kn, &lds[nb][1][c0]); GLD16(pA0l+h16+kn, &lds[nb][1][c1]); }
        FENCE_MFMA;
        MM3(0,2,a0h,a0l,bh2,bl2); MM3(0,3,a0h,a0l,bh3,bl3);
        MM3(1,2,a1h,a1l,bh2,bl2); MM3(1,3,a1h,a1l,bh3,bl3);
        ENDPH;
        // ---- phase 2 (mf 2,3 x nf 0,1) ----
        ARD(1);
        if (pf){ GLD16(pB0h+kn, &lds[nb][2][c0]); GLD16(pB0h+h16+kn, &lds[nb][2][c1]); }
        FENCE_MFMA;
        MM3(2,0,a0h,a0l,bh0,bl0); MM3(2,1,a0h,a0l,bh1,bl1);
        MM3(3,0,a1h,a1l,bh0,bl0); MM3(3,1,a1h,a1l,bh1,bl1);
        ENDPH;
        // ---- phase 3 (mf 2,3 x nf 2,3) ----
        if (pf){ GLD16(pB0l+kn, &lds[nb][3][c0]); GLD16(pB0l+h16+kn, &lds[nb][3][c1]); }
        FENCE_MFMA;
        MM3(2,2,a0h,a0l,bh2,bl2); MM3(2,3,a0h,a0l,bh3,bl3);
        MM3(3,2,a1h,a1l,bh2,bl2); MM3(3,3,a1h,a1l,bh3,bl3);
        ENDPH;
        // ---- phase 4 (mf 4,5 x nf 0,1) ----
        ARD(2);
        FENCE_MFMA;
        MM3(4,0,a0h,a0l,bh0,bl0); MM3(4,1,a0h,a0l,bh1,bl1);
        MM3(5,0,a1h,a1l,bh0,bl0); MM3(5,1,a1h,a1l,bh1,bl1);
        ENDPH;
        // ---- phase 5 (mf 4,5 x nf 2,3) ----
        FENCE_MFMA;
        MM3(4,2,a0h,a0l,bh2,bl2); MM3(4,3,a0h,a0l,bh3,bl3);
        MM3(5,2,a1h,a1l,bh2,bl2); MM3(5,3,a1h,a1l,bh3,bl3);
        ENDPH;
        // ---- phase 6 (mf 6,7 x nf 0,1) ----
        ARD(3);
        FENCE_MFMA;
        MM3(6,0,a0h,a0l,bh0,bl0); MM3(6,1,a0h,a0l,bh1,bl1);
        MM3(7,0,a1h,a1l,bh0,bl0); MM3(7,1,a1h,a1l,bh1,bl1);
        ENDPH;
        // ---- phase 7 (mf 6,7 x nf 2,3) ----
        FENCE_MFMA;
        MM3(6,2,a0h,a0l,bh2,bl2); MM3(6,3,a0h,a0l,bh3,bl3);
        MM3(7,2,a1h,a1l,bh2,bl2); MM3(7,3,a1h,a1l,bh3,bl3);
        __builtin_amdgcn_s_setprio(0);
        if (pf) asm volatile("s_waitcnt vmcnt(0)" ::: "memory");
        __builtin_amdgcn_s_barrier();
    }

    // ---- epilogue ----
    #pragma unroll
    for (int nf=0; nf<4; nf++){
        const int col = n0 + nc + nf*16 + lrow;
        if (MODE == 1){
            float gam = sqrtf(1.0f - expf(-2.0f*expf(nu_log[col & 255])));
            float t1v = t1[col], t2v = t2[col];
            float* dst = (col < 256) ? outA : outB;
            int c2 = col & 255;
            #pragma unroll
            for (int mf=0;mf<8;mf++){
                #pragma unroll
                for (int j=0;j<4;j++){
                    int row = r0 + mr + mf*16 + lgrp*4 + j;
                    float rs = rs_arr[row], muv = mu_arr[row];
                    dst[(size_t)row*256 + c2] = gam * (rs*acc[mf][nf][j] - rs*muv*t1v + t2v);
                }
            }
        } else if (MODE == 2){
            float dsk = d_skip[col], sc = ln_scale[col], bi = ln_bias[col];
            #pragma unroll
            for (int mf=0;mf<8;mf++){
                #pragma unroll
                for (int j=0;j<4;j++){
                    int row = r0 + mr + mf*16 + lgrp*4 + j;
                    size_t idx = (size_t)row*256 + col;
                    float rs = rs_arr[row], muv = mu_arr[row];
                    float xn = (x[idx] - muv)*rs*sc + bi;
                    float g = gelu_tanh(acc[mf][nf][j] + dsk*xn);
                    uint16_t hb = bf16_rne(g);
                    gh[idx] = (short)hb;
                    gl[idx] = (short)bf16_rne(g - bf16_to_f(hb));
                }
            }
        } else {
            float bb = bvec[col];
            #pragma unroll
            for (int mf=0;mf<8;mf++){
                #pragma unroll
                for (int j=0;j<4;j++){
                    int row = r0 + mr + mf*16 + lgrp*4 + j;
                    size_t idx = (size_t)row*256 + col;
                    outA[idx] = acc[mf][nf][j] + bb + x[idx];
                }
            }
        }
    }
}

// ---- scan kernels ----------------------------------------------------------
__global__ __launch_bounds__(256)
void k_scan_local(const float* __restrict__ nu_log, const float* __restrict__ theta_log,
                  const float* __restrict__ bu_re, const float* __restrict__ bu_im,
                  float* __restrict__ e_re, float* __restrict__ e_im){
    int h = threadIdx.x;
    int bc = blockIdx.x;
    int b = bc / NC, c = bc % NC;
    float en = expf(nu_log[h]);
    float mag = expf(-en), th = expf(theta_log[h]);
    float lam_re = mag * cosf(th), lam_im = mag * sinf(th);
    const float* pr = bu_re + (size_t)(b*Lsz + c*CL)*D + h;
    const float* pi = bu_im + (size_t)(b*Lsz + c*CL)*D + h;
    float sr = 0.f, si = 0.f;
    #pragma unroll 4
    for (int tt=0; tt<CL; tt++){
        float ur = pr[(size_t)tt*D], ui = pi[(size_t)tt*D];
        float nsr = fmaf(lam_re, sr, fmaf(-lam_im, si, ur));
        float nsi = fmaf(lam_re, si, fmaf( lam_im, sr, ui));
        sr = nsr; si = nsi;
    }
    e_re[(c*Bsz + b)*D + h] = sr;
    e_im[(c*Bsz + b)*D + h] = si;
}

__global__ __launch_bounds__(256)
void k_scan_combine(const float* __restrict__ nu_log, const float* __restrict__ theta_log,
                    const float* __restrict__ e_re, const float* __restrict__ e_im,
                    float* __restrict__ p_re, float* __restrict__ p_im){
    int h = threadIdx.x;
    int b = blockIdx.x;
    double en = exp((double)nu_log[h]);
    double th = exp((double)theta_log[h]);
    double mag = exp(-en);
    double lr = mag*cos(th), li = mag*sin(th);
    double ar = 1.0, ai = 0.0;               // lam^CL
    for (int i=0;i<CL;i++){
        double nr = ar*lr - ai*li;
        double ni = ar*li + ai*lr;
        ar = nr; ai = ni;
    }
    double sr = 0.0, si = 0.0;
    for (int c=0;c<NC;c++){
        int idx = (c*Bsz + b)*D + h;
        p_re[idx] = (float)sr; p_im[idx] = (float)si;
        double er = e_re[idx], ei = e_im[idx];
        double nr = ar*sr - ai*si + er;
        double ni = ar*si + ai*sr + ei;
        sr = nr; si = ni;
    }
}

// re-scan with prefix; write h IN PLACE over bu planes as bf16 pairs:
//   bu_re dword(col h) <- (bf16(h_re), bf16(h_im))   [hi plane, K-interleaved]
//   bu_im dword(col h) <- (lo residuals)             [lo plane]
__global__ __launch_bounds__(256)
void k_scan_apply(const float* __restrict__ nu_log, const float* __restrict__ theta_log,
                  const float* __restrict__ p_re, const float* __restrict__ p_im,
                  float* __restrict__ bu_re, float* __restrict__ bu_im){
    int h = threadIdx.x;
    int bc = blockIdx.x;
    int b = bc / NC, c = bc % NC;
    float en = expf(nu_log[h]);
    float mag = expf(-en), th = expf(theta_log[h]);
    float lam_re = mag * cosf(th), lam_im = mag * sinf(th);
    int pidx = (c*Bsz + b)*D + h;
    float sr = p_re[pidx], si = p_im[pidx];
    float* pr = bu_re + (size_t)(b*Lsz + c*CL)*D + h;
    float* pi = bu_im + (size_t)(b*Lsz + c*CL)*D + h;
    #pragma unroll 4
    for (int tt=0; tt<CL; tt++){
        float ur = pr[(size_t)tt*D], ui = pi[(size_t)tt*D];
        float nsr = fmaf(lam_re, sr, fmaf(-lam_im, si, ur));
        float nsi = fmaf(lam_re, si, fmaf( lam_im, sr, ui));
        sr = nsr; si = nsi;
        uint16_t rh = bf16_rne(sr), ih = bf16_rne(si);
        uint16_t rl = bf16_rne(sr - bf16_to_f(rh));
        uint16_t il = bf16_rne(si - bf16_to_f(ih));
        *(uint32_t*)&pr[(size_t)tt*D] = (uint32_t)rh | ((uint32_t)ih << 16);
        *(uint32_t*)&pi[(size_t)tt*D] = (uint32_t)rl | ((uint32_t)il << 16);
    }
}

extern "C" void kernel_launch(void* const* d_in, const int* in_sizes, int n_in,
                              void* d_out, int out_size, void* d_ws, size_t ws_size,
                              hipStream_t stream){
    const float* x         = (const float*)d_in[0];
    const float* ln_scale  = (const float*)d_in[1];
    const float* ln_bias   = (const float*)d_in[2];
    const float* nu_log    = (const float*)d_in[3];
    const float* theta_log = (const float*)d_in[4];
    const float* B_re      = (const float*)d_in[5];
    const float* B_im      = (const float*)d_in[6];
    const float* C_re      = (const float*)d_in[7];
    const float* C_im      = (const float*)d_in[8];
    const float* D_skip    = (const float*)d_in[9];
    const float* W         = (const float*)d_in[10];
    const float* bvec      = (const float*)d_in[11];
    float* out = (float*)d_out;

    char* base = (char*)d_ws;
    size_t off = 0;
    auto alloc = [&](size_t bytes)->char*{
        char* p = base + off;
        off += (bytes + 255) & ~(size_t)255;
        return p;
    };
    float*  bu_re = (float*)alloc((size_t)NROWS*D*4);   // later: h hi-plane
    float*  bu_im = (float*)alloc((size_t)NROWS*D*4);   // later: h lo-plane
    short*  xg_hi = (short*)alloc((size_t)NROWS*D*2);   // xhi, later ghi
    short*  xg_lo = (short*)alloc((size_t)NROWS*D*2);   // xlo, later glo
    float*  mu_a  = (float*)alloc((size_t)NROWS*4);
    float*  rs_a  = (float*)alloc((size_t)NROWS*4);
    float*  e_re  = (float*)alloc((size_t)NC*Bsz*D*4);
    float*  e_im  = (float*)alloc((size_t)NC*Bsz*D*4);
    float*  p_re  = (float*)alloc((size_t)NC*Bsz*D*4);
    float*  p_im  = (float*)alloc((size_t)NC*Bsz*D*4);
    float*  t1    = (float*)alloc(512*4);
    float*  t2    = (float*)alloc(512*4);
    short*  b1_hi = (short*)alloc(512*256*2);
    short*  b1_lo = (short*)alloc(512*256*2);
    short*  b2_hi = (short*)alloc(256*512*2);
    short*  b2_lo = (short*)alloc(256*512*2);
    short*  b3_hi = (short*)alloc(256*256*2);
    short*  b3_lo = (short*)alloc(256*256*2);

    k_prep<<<512, 256, 0, stream>>>(B_re, B_im, C_re, C_im, W, ln_scale,
                                    b1_hi, b1_lo, b2_hi, b2_lo, b3_hi, b3_lo);
    k_prep_t<<<2, 256, 0, stream>>>(B_re, B_im, ln_scale, ln_bias, t1, t2);
    k_stats<<<NROWS/16, 256, 0, stream>>>(x, mu_a, rs_a, xg_hi, xg_lo);

    // GEMM1: Bu = gamma*(LN(x) @ B1^T)   (N=512: cols 0-255 re, 256-511 im)
    k_gemm<1><<<(NROWS/256)*2, 512, 0, stream>>>(
        xg_hi, xg_lo, b1_hi, b1_lo, x, mu_a, rs_a, t1, t2, nu_log,
        ln_scale, ln_bias, D_skip, bvec, bu_re, bu_im, nullptr, nullptr);

    k_scan_local<<<Bsz*NC, 256, 0, stream>>>(nu_log, theta_log, bu_re, bu_im, e_re, e_im);
    k_scan_combine<<<Bsz, 256, 0, stream>>>(nu_log, theta_log, e_re, e_im, p_re, p_im);
    k_scan_apply<<<Bsz*NC, 256, 0, stream>>>(nu_log, theta_log, p_re, p_im, bu_re, bu_im);

    // GEMM2: y = Re(h C^T) + Dskip*xn -> gelu -> g planes (alias x-planes)
    k_gemm<2><<<NROWS/256, 512, 0, stream>>>(
        (const short*)bu_re, (const short*)bu_im, b2_hi, b2_lo, x,
        mu_a, rs_a, t1, t2, nu_log, ln_scale, ln_bias, D_skip, bvec,
        nullptr, nullptr, xg_hi, xg_lo);

    // GEMM3: out = g W^T + b + x
    k_gemm<3><<<NROWS/256, 512, 0, stream>>>(
        xg_hi, xg_lo, b3_hi, b3_lo, x, mu_a, rs_a, t1, t2, nu_log,
        ln_scale, ln_bias, D_skip, bvec, out, nullptr, nullptr, nullptr);
}

// Round 7
// 451.722 us; speedup vs baseline: 1.0061x; 1.0061x over previous
//
#include <hip/hip_runtime.h>
#include <math.h>
#include <stdint.h>

#define Bsz 8
#define Lsz 8192
#define D 256
#define NROWS (Bsz*Lsz)      // 65536
#define NC 128               // chunks per sequence
#define CL (Lsz/NC)          // 64
#define LN_EPS 1e-6f

typedef float f32x4 __attribute__((ext_vector_type(4)));
typedef short bf16x8 __attribute__((ext_vector_type(8)));
typedef uint32_t __attribute__((address_space(3))) as3_u32;
typedef const uint32_t __attribute__((address_space(1))) as1_u32;

__device__ __forceinline__ float gelu_tanh(float v){
    const float k0 = 0.7978845608028654f;   // sqrt(2/pi)
    const float k1 = 0.044715f;
    float inner = k0 * fmaf(k1*v*v, v, v);
    return 0.5f * v * (1.0f + tanhf(inner));
}
__device__ __forceinline__ uint16_t bf16_rne(float f){
    uint32_t u = __float_as_uint(f);
    return (uint16_t)((u + 0x7fffu + ((u>>16)&1u)) >> 16);
}
__device__ __forceinline__ float bf16_to_f(uint16_t h){
    return __uint_as_float(((uint32_t)h)<<16);
}

// ---- prep: split weights to bf16 hi/lo planes (B-layout [N][K]) ------------
__global__ __launch_bounds__(256)
void k_prep(const float* __restrict__ B_re, const float* __restrict__ B_im,
            const float* __restrict__ C_re, const float* __restrict__ C_im,
            const float* __restrict__ W, const float* __restrict__ ln_scale,
            short* __restrict__ b1_hi, short* __restrict__ b1_lo,
            short* __restrict__ b2_hi, short* __restrict__ b2_lo,
            short* __restrict__ b3_hi, short* __restrict__ b3_lo){
    int i = blockIdx.x*256 + threadIdx.x;   // 131072
    {   // b1 [512][256]
        int n = i >> 8, d = i & 255;
        float v = (n < 256 ? B_re[n*256 + d] : B_im[(n-256)*256 + d]) * ln_scale[d];
        uint16_t hi = bf16_rne(v);
        b1_hi[i] = (short)hi;
        b1_lo[i] = (short)bf16_rne(v - bf16_to_f(hi));
    }
    {   // b2 [256][512], K-interleaved re/im
        int n = i >> 9, k = i & 511, h = k >> 1;
        float v = (k & 1) ? -C_im[n*256 + h] : C_re[n*256 + h];
        uint16_t hi = bf16_rne(v);
        b2_hi[i] = (short)hi;
        b2_lo[i] = (short)bf16_rne(v - bf16_to_f(hi));
    }
    if (i < 256*256){   // b3 [256][256]
        float v = W[i];
        uint16_t hi = bf16_rne(v);
        b3_hi[i] = (short)hi;
        b3_lo[i] = (short)bf16_rne(v - bf16_to_f(hi));
    }
}

__global__ __launch_bounds__(256)
void k_prep_t(const float* __restrict__ B_re, const float* __restrict__ B_im,
              const float* __restrict__ ln_scale, const float* __restrict__ ln_bias,
              float* __restrict__ t1, float* __restrict__ t2){
    int n = blockIdx.x*256 + threadIdx.x;
    if (n >= 512) return;
    const float* src = (n < 256) ? &B_re[n*256] : &B_im[(n-256)*256];
    float s1 = 0.f, s2 = 0.f;
    for (int d = 0; d < 256; d++){
        float b = src[d];
        s1 = fmaf(ln_scale[d], b, s1);
        s2 = fmaf(ln_bias[d],  b, s2);
    }
    t1[n] = s1; t2[n] = s2;
}

// ---- stats: LN (mu, rstd) per row + materialize xhi/xlo bf16 planes --------
__global__ __launch_bounds__(256)
void k_stats(const float* __restrict__ x, float* __restrict__ mu_arr,
             float* __restrict__ rstd_arr, short* __restrict__ xhi,
             short* __restrict__ xlo){
    int r0 = blockIdx.x * 16;
    int t = threadIdx.x;
    int wave = t >> 6, lane = t & 63;
    for (int rr = wave; rr < 16; rr += 4){
        const float* xr = x + (size_t)(r0 + rr) * D;
        float v[4]; float s = 0.f;
        #pragma unroll
        for (int i=0;i<4;i++){ v[i] = xr[lane + 64*i]; s += v[i]; }
        #pragma unroll
        for (int off=32; off; off>>=1) s += __shfl_xor(s, off);
        float mu = s * (1.0f/D);
        float vs = 0.f;
        #pragma unroll
        for (int i=0;i<4;i++){ float dd = v[i]-mu; vs += dd*dd; }
        #pragma unroll
        for (int off=32; off; off>>=1) vs += __shfl_xor(vs, off);
        float rstd = rsqrtf(vs*(1.0f/D) + LN_EPS);
        if (lane == 0){ mu_arr[r0+rr] = mu; rstd_arr[r0+rr] = rstd; }
        size_t rb = (size_t)(r0+rr)*D;
        #pragma unroll
        for (int i=0;i<4;i++){
            int dd = lane + 64*i;
            uint16_t hb = bf16_rne(v[i]);
            xhi[rb+dd] = (short)hb;
            xlo[rb+dd] = (short)bf16_rne(v[i] - bf16_to_f(hb));
        }
    }
}

// ---- 128x128 MFMA GEMM: m97-replica, single-buf LDS, 3 blocks/CU -----------
// 256 threads (4 waves, 64x64 wave tiles). LDS = 4 frag-major planes x 8KB =
// 32KB single-buffered. Per K-step: __syncthreads -> 8 global_load_lds ->
// __syncthreads (compiler drains vmcnt) -> ds_read frags + 48 MFMA (compiler
// schedules lgkmcnt interleave). Latency hiding comes from 3 blocks/CU
// (m114 cross-block overlap), NOT intra-block pipelining.
// Frag-major chunk: 16B chunk c = F*64 + kg*16 + r holds row F*16+r, k-slice
// kg (8 shorts) -> frag ds_read_b128 is 256B-contiguous per 16-lane group.
#define GLD16(gp, lp) __builtin_amdgcn_global_load_lds((as1_u32*)(gp), (as3_u32*)(lp), 16, 0, 0)

template<int MODE>
__global__ __launch_bounds__(256, 3)
void k_gemm(const short* __restrict__ Ahi_g, const short* __restrict__ Alo_g,
            const short* __restrict__ Bhi_g, const short* __restrict__ Blo_g,
            const float* __restrict__ x,
            const float* __restrict__ mu_arr, const float* __restrict__ rs_arr,
            const float* __restrict__ t1, const float* __restrict__ t2,
            const float* __restrict__ nu_log,
            const float* __restrict__ ln_scale, const float* __restrict__ ln_bias,
            const float* __restrict__ d_skip, const float* __restrict__ bvec,
            float* __restrict__ outA, float* __restrict__ outB,
            short* __restrict__ gh, short* __restrict__ gl){
    constexpr int K   = (MODE==2) ? 512 : 256;
    constexpr int NYB = (MODE==1) ? 4 : 2;
    constexpr int NT  = K/32;
    __shared__ __align__(16) short Ah[4096];
    __shared__ __align__(16) short Al[4096];
    __shared__ __align__(16) short Bh[4096];
    __shared__ __align__(16) short Bl[4096];
    const int t = threadIdx.x;
    const int wv = t >> 6, lane = t & 63;
    const int lgrp = lane >> 4, lrow = lane & 15;
    const int r0 = (blockIdx.x / NYB) * 128;   // NYB consecutive blocks share A
    const int n0 = (blockIdx.x % NYB) * 128;
    const int mr = (wv >> 1) * 64;
    const int nc = (wv & 1) * 64;
    const int ga = (wv >> 1) * 4, gb = (wv & 1) * 4;

    // staging sources: wave wv covers F=wv (rows wv*16..+15) and F=4+wv
    const short* paH = Ahi_g + (size_t)(r0 + wv*16 + lrow)*K + lgrp*8;
    const short* paL = Alo_g + (size_t)(r0 + wv*16 + lrow)*K + lgrp*8;
    const short* pbH = Bhi_g + (size_t)(n0 + wv*16 + lrow)*K + lgrp*8;
    const short* pbL = Blo_g + (size_t)(n0 + wv*16 + lrow)*K + lgrp*8;
    const size_t h64 = (size_t)64*K;          // +64 rows (F=4+wv)
    const int c0 = wv*512, c1 = 2048 + wv*512; // LDS dests (shorts)

    f32x4 acc[4][4];
    #pragma unroll
    for (int mf=0;mf<4;mf++)
    #pragma unroll
    for (int nf=0;nf<4;nf++) acc[mf][nf] = (f32x4){0.f,0.f,0.f,0.f};

    #pragma unroll 1
    for (int kt = 0; kt < NT; ++kt){
        const int ko = kt*32;
        __syncthreads();                       // prev step done reading LDS
        GLD16(paH + ko, &Ah[c0]); GLD16(paH + h64 + ko, &Ah[c1]);
        GLD16(paL + ko, &Al[c0]); GLD16(paL + h64 + ko, &Al[c1]);
        GLD16(pbH + ko, &Bh[c0]); GLD16(pbH + h64 + ko, &Bh[c1]);
        GLD16(pbL + ko, &Bl[c0]); GLD16(pbL + h64 + ko, &Bl[c1]);
        __syncthreads();                       // compiler drains vmcnt here

        bf16x8 ahv[4], alv[4], bhv[4], blv[4];
        #pragma unroll
        for (int mf=0;mf<4;mf++){
            const int c = ((ga+mf)*64 + lgrp*16 + lrow)*8;
            ahv[mf] = *(const bf16x8*)&Ah[c];
            alv[mf] = *(const bf16x8*)&Al[c];
        }
        #pragma unroll
        for (int nf=0;nf<4;nf++){
            const int c = ((gb+nf)*64 + lgrp*16 + lrow)*8;
            bhv[nf] = *(const bf16x8*)&Bh[c];
            blv[nf] = *(const bf16x8*)&Bl[c];
        }
        #pragma unroll
        for (int mf=0;mf<4;mf++)
        #pragma unroll
        for (int nf=0;nf<4;nf++){
            acc[mf][nf] = __builtin_amdgcn_mfma_f32_16x16x32_bf16(ahv[mf], bhv[nf], acc[mf][nf], 0,0,0);
            acc[mf][nf] = __builtin_amdgcn_mfma_f32_16x16x32_bf16(ahv[mf], blv[nf], acc[mf][nf], 0,0,0);
            acc[mf][nf] = __builtin_amdgcn_mfma_f32_16x16x32_bf16(alv[mf], bhv[nf], acc[mf][nf], 0,0,0);
        }
    }

    // ---- epilogue ----
    #pragma unroll
    for (int nf=0; nf<4; nf++){
        const int col = n0 + nc + nf*16 + lrow;    // MODE1: 0..511 else 0..255
        if (MODE == 1){
            float gam = sqrtf(1.0f - expf(-2.0f*expf(nu_log[col & 255])));
            float t1v = t1[col], t2v = t2[col];
            float* dst = (col < 256) ? outA : outB;
            int c2 = col & 255;
            #pragma unroll
            for (int mf=0;mf<4;mf++){
                #pragma unroll
                for (int j=0;j<4;j++){
                    int row = r0 + mr + mf*16 + lgrp*4 + j;
                    float rs = rs_arr[row], muv = mu_arr[row];
                    dst[(size_t)row*256 + c2] = gam * (rs*acc[mf][nf][j] - rs*muv*t1v + t2v);
                }
            }
        } else if (MODE == 2){
            float dsk = d_skip[col], sc = ln_scale[col], bi = ln_bias[col];
            #pragma unroll
            for (int mf=0;mf<4;mf++){
                #pragma unroll
                for (int j=0;j<4;j++){
                    int row = r0 + mr + mf*16 + lgrp*4 + j;
                    size_t idx = (size_t)row*256 + col;
                    float rs = rs_arr[row], muv = mu_arr[row];
                    float xn = (x[idx] - muv)*rs*sc + bi;
                    float g = gelu_tanh(acc[mf][nf][j] + dsk*xn);
                    uint16_t hb = bf16_rne(g);
                    gh[idx] = (short)hb;
                    gl[idx] = (short)bf16_rne(g - bf16_to_f(hb));
                }
            }
        } else {
            float bb = bvec[col];
            #pragma unroll
            for (int mf=0;mf<4;mf++){
                #pragma unroll
                for (int j=0;j<4;j++){
                    int row = r0 + mr + mf*16 + lgrp*4 + j;
                    size_t idx = (size_t)row*256 + col;
                    outA[idx] = acc[mf][nf][j] + bb + x[idx];
                }
            }
        }
    }
}

// ---- scan kernels ----------------------------------------------------------
__global__ __launch_bounds__(256)
void k_scan_local(const float* __restrict__ nu_log, const float* __restrict__ theta_log,
                  const float* __restrict__ bu_re, const float* __restrict__ bu_im,
                  float* __restrict__ e_re, float* __restrict__ e_im){
    int h = threadIdx.x;
    int bc = blockIdx.x;
    int b = bc / NC, c = bc % NC;
    float en = expf(nu_log[h]);
    float mag = expf(-en), th = expf(theta_log[h]);
    float lam_re = mag * cosf(th), lam_im = mag * sinf(th);
    const float* pr = bu_re + (size_t)(b*Lsz + c*CL)*D + h;
    const float* pi = bu_im + (size_t)(b*Lsz + c*CL)*D + h;
    float sr = 0.f, si = 0.f;
    #pragma unroll 4
    for (int tt=0; tt<CL; tt++){
        float ur = pr[(size_t)tt*D], ui = pi[(size_t)tt*D];
        float nsr = fmaf(lam_re, sr, fmaf(-lam_im, si, ur));
        float nsi = fmaf(lam_re, si, fmaf( lam_im, sr, ui));
        sr = nsr; si = nsi;
    }
    e_re[(c*Bsz + b)*D + h] = sr;
    e_im[(c*Bsz + b)*D + h] = si;
}

__global__ __launch_bounds__(256)
void k_scan_combine(const float* __restrict__ nu_log, const float* __restrict__ theta_log,
                    const float* __restrict__ e_re, const float* __restrict__ e_im,
                    float* __restrict__ p_re, float* __restrict__ p_im){
    int h = threadIdx.x;
    int b = blockIdx.x;
    double en = exp((double)nu_log[h]);
    double th = exp((double)theta_log[h]);
    double mag = exp(-en);
    double lr = mag*cos(th), li = mag*sin(th);
    double ar = 1.0, ai = 0.0;               // lam^CL
    for (int i=0;i<CL;i++){
        double nr = ar*lr - ai*li;
        double ni = ar*li + ai*lr;
        ar = nr; ai = ni;
    }
    double sr = 0.0, si = 0.0;
    for (int c=0;c<NC;c++){
        int idx = (c*Bsz + b)*D + h;
        p_re[idx] = (float)sr; p_im[idx] = (float)si;
        double er = e_re[idx], ei = e_im[idx];
        double nr = ar*sr - ai*si + er;
        double ni = ar*si + ai*sr + ei;
        sr = nr; si = ni;
    }
}

// re-scan with prefix; write h IN PLACE over bu planes as bf16 pairs:
//   bu_re dword(col h) <- (bf16(h_re), bf16(h_im))   [hi plane, K-interleaved]
//   bu_im dword(col h) <- (lo residuals)             [lo plane]
__global__ __launch_bounds__(256)
void k_scan_apply(const float* __restrict__ nu_log, const float* __restrict__ theta_log,
                  const float* __restrict__ p_re, const float* __restrict__ p_im,
                  float* __restrict__ bu_re, float* __restrict__ bu_im){
    int h = threadIdx.x;
    int bc = blockIdx.x;
    int b = bc / NC, c = bc % NC;
    float en = expf(nu_log[h]);
    float mag = expf(-en), th = expf(theta_log[h]);
    float lam_re = mag * cosf(th), lam_im = mag * sinf(th);
    int pidx = (c*Bsz + b)*D + h;
    float sr = p_re[pidx], si = p_im[pidx];
    float* pr = bu_re + (size_t)(b*Lsz + c*CL)*D + h;
    float* pi = bu_im + (size_t)(b*Lsz + c*CL)*D + h;
    #pragma unroll 4
    for (int tt=0; tt<CL; tt++){
        float ur = pr[(size_t)tt*D], ui = pi[(size_t)tt*D];
        float nsr = fmaf(lam_re, sr, fmaf(-lam_im, si, ur));
        float nsi = fmaf(lam_re, si, fmaf( lam_im, sr, ui));
        sr = nsr; si = nsi;
        uint16_t rh = bf16_rne(sr), ih = bf16_rne(si);
        uint16_t rl = bf16_rne(sr - bf16_to_f(rh));
        uint16_t il = bf16_rne(si - bf16_to_f(ih));
        *(uint32_t*)&pr[(size_t)tt*D] = (uint32_t)rh | ((uint32_t)ih << 16);
        *(uint32_t*)&pi[(size_t)tt*D] = (uint32_t)rl | ((uint32_t)il << 16);
    }
}

extern "C" void kernel_launch(void* const* d_in, const int* in_sizes, int n_in,
                              void* d_out, int out_size, void* d_ws, size_t ws_size,
                              hipStream_t stream){
    const float* x         = (const float*)d_in[0];
    const float* ln_scale  = (const float*)d_in[1];
    const float* ln_bias   = (const float*)d_in[2];
    const float* nu_log    = (const float*)d_in[3];
    const float* theta_log = (const float*)d_in[4];
    const float* B_re      = (const float*)d_in[5];
    const float* B_im      = (const float*)d_in[6];
    const float* C_re      = (const float*)d_in[7];
    const float* C_im      = (const float*)d_in[8];
    const float* D_skip    = (const float*)d_in[9];
    const float* W         = (const float*)d_in[10];
    const float* bvec      = (const float*)d_in[11];
    float* out = (float*)d_out;

    char* base = (char*)d_ws;
    size_t off = 0;
    auto alloc = [&](size_t bytes)->char*{
        char* p = base + off;
        off += (bytes + 255) & ~(size_t)255;
        return p;
    };
    float*  bu_re = (float*)alloc((size_t)NROWS*D*4);   // later: h hi-plane
    float*  bu_im = (float*)alloc((size_t)NROWS*D*4);   // later: h lo-plane
    short*  xg_hi = (short*)alloc((size_t)NROWS*D*2);   // xhi, later ghi
    short*  xg_lo = (short*)alloc((size_t)NROWS*D*2);   // xlo, later glo
    float*  mu_a  = (float*)alloc((size_t)NROWS*4);
    float*  rs_a  = (float*)alloc((size_t)NROWS*4);
    float*  e_re  = (float*)alloc((size_t)NC*Bsz*D*4);
    float*  e_im  = (float*)alloc((size_t)NC*Bsz*D*4);
    float*  p_re  = (float*)alloc((size_t)NC*Bsz*D*4);
    float*  p_im  = (float*)alloc((size_t)NC*Bsz*D*4);
    float*  t1    = (float*)alloc(512*4);
    float*  t2    = (float*)alloc(512*4);
    short*  b1_hi = (short*)alloc(512*256*2);
    short*  b1_lo = (short*)alloc(512*256*2);
    short*  b2_hi = (short*)alloc(256*512*2);
    short*  b2_lo = (short*)alloc(256*512*2);
    short*  b3_hi = (short*)alloc(256*256*2);
    short*  b3_lo = (short*)alloc(256*256*2);

    k_prep<<<512, 256, 0, stream>>>(B_re, B_im, C_re, C_im, W, ln_scale,
                                    b1_hi, b1_lo, b2_hi, b2_lo, b3_hi, b3_lo);
    k_prep_t<<<2, 256, 0, stream>>>(B_re, B_im, ln_scale, ln_bias, t1, t2);
    k_stats<<<NROWS/16, 256, 0, stream>>>(x, mu_a, rs_a, xg_hi, xg_lo);

    // GEMM1: Bu = gamma*(LN(x) @ B1^T)   (N=512: cols 0-255 re, 256-511 im)
    k_gemm<1><<<(NROWS/128)*4, 256, 0, stream>>>(
        xg_hi, xg_lo, b1_hi, b1_lo, x, mu_a, rs_a, t1, t2, nu_log,
        ln_scale, ln_bias, D_skip, bvec, bu_re, bu_im, nullptr, nullptr);

    k_scan_local<<<Bsz*NC, 256, 0, stream>>>(nu_log, theta_log, bu_re, bu_im, e_re, e_im);
    k_scan_combine<<<Bsz, 256, 0, stream>>>(nu_log, theta_log, e_re, e_im, p_re, p_im);
    k_scan_apply<<<Bsz*NC, 256, 0, stream>>>(nu_log, theta_log, p_re, p_im, bu_re, bu_im);

    // GEMM2: y = Re(h C^T) + Dskip*xn -> gelu -> g planes (alias x-planes)
    k_gemm<2><<<(NROWS/128)*2, 256, 0, stream>>>(
        (const short*)bu_re, (const short*)bu_im, b2_hi, b2_lo, x,
        mu_a, rs_a, t1, t2, nu_log, ln_scale, ln_bias, D_skip, bvec,
        nullptr, nullptr, xg_hi, xg_lo);

    // GEMM3: out = g W^T + b + x
    k_gemm<3><<<(NROWS/128)*2, 256, 0, stream>>>(
        xg_hi, xg_lo, b3_hi, b3_lo, x, mu_a, rs_a, t1, t2, nu_log,
        ln_scale, ln_bias, D_skip, bvec, out, nullptr, nullptr, nullptr);
}